// Round 1
// baseline (1417.972 us; speedup 1.0000x reference)
//
#include <hip/hip_runtime.h>
#include <hip/hip_bf16.h>

#define NB 8
#define NT 128
#define NS 128
#define NSTEP 127
#define TPRED 4
#define TOUT 123
#define RROWS 16
#define NBLK 64
#define NTHR 512

typedef __attribute__((ext_vector_type(4))) float f32x4;
typedef __attribute__((ext_vector_type(8))) short s16x8;

// workspace layout (bytes)
#define WS_WTC 0                          // bf16 [512][384]  cell weights, K-permuted, transposed
#define WS_WT1 (512*384*2)                // bf16 [128][128]  W1 transposed
#define WS_HB  (WS_WT1 + 128*128*2)       // bf16 [64 blk][2 side][2 parity][128]
#define WS_OSC (WS_HB + 64*2*2*128*2)     // f32  [64 blk][2 parity]  out[last][0] scalar
#define WS_FLG (WS_OSC + 64*2*4)          // u32  [64 blk][16]  (0=side0 ready,1=side1 ready,2=out ready)

__device__ __forceinline__ unsigned swz(unsigned off) {
    // XOR-swizzle: row-major [*][128] bf16 tiles, breaks 256B-stride bank conflicts (G4)
    return off ^ (((off >> 8) & 7u) << 4);
}

__global__ void init_weights(const float* __restrict__ Wc, const float* __restrict__ W1,
                             __hip_bfloat16* __restrict__ WTc, __hip_bfloat16* __restrict__ WT1)
{
    int i = blockIdx.x * blockDim.x + threadIdx.x;
    if (i < 512*384) {
        int n = i / 384, k = i % 384;
        // K order: 0..127 -> h_before (W rows 261..388), 128..255 -> h (5..132), 256..383 -> h_after (133..260)
        int src = (k < 128) ? (261 + k) : ((k < 256) ? (5 + (k - 128)) : (133 + (k - 256)));
        WTc[n*384 + k] = __float2bfloat16(Wc[src*512 + n]);
    } else {
        int q = i - 512*384;
        if (q < 128*128) {
            int n = q >> 7, k = q & 127;
            WT1[n*128 + k] = __float2bfloat16(W1[k*128 + n]);
        }
    }
}

__global__ __launch_bounds__(NTHR) void lstm_persist(
    const float* __restrict__ input, const float* __restrict__ Wc,
    const float* __restrict__ bc, const float* __restrict__ b1v,
    const float* __restrict__ W2, const float* __restrict__ b2,
    float* __restrict__ outp,
    const __hip_bfloat16* __restrict__ WTc, const __hip_bfloat16* __restrict__ WT1,
    __hip_bfloat16* hbuf, float* osc, unsigned* flags)
{
    __shared__ __align__(16) __hip_bfloat16 h_loc[18*128];   // rows: 0=left bnd, 1..16=own, 17=right bnd (swizzled)
    __shared__ __align__(16) __hip_bfloat16 relu_l[16*128];  // relu(h@W1+b1) (swizzled)
    __shared__ float xl[RROWS*5];
    __shared__ float xnl[3];
    __shared__ float outl[RROWS*3];
    __shared__ float w2l[3*128];
    __shared__ float b2l[3];

    const int tid  = threadIdx.x;
    const int blk  = blockIdx.x;
    const int b    = blk & 7;      // batch: consecutive blk -> same chunk diff batch -> batch spans one XCD slot
    const int ci   = blk >> 3;     // chunk along s
    const int s0   = ci * RROWS;
    const int lane = tid & 63;
    const int w    = tid >> 6;     // wave 0..7
    const int arow = lane & 15;
    const int kgrp = lane >> 4;
    const int colh = (w << 4) + arow;   // hid column 0..127 owned by this lane

    for (int i = tid; i < 18*128; i += NTHR) ((unsigned short*)h_loc)[i] = 0;
    if (tid < 384) w2l[tid] = W2[(tid & 127)*3 + (tid >> 7)];   // w2l[p*128+k] = W2[k][p]
    if (tid >= 384 && tid < 387) b2l[tid - 384] = b2[tid - 384];

    // step-invariant per-lane constants: x-part weights + biases for this hid column, all 4 gates
    float wxr[4][5], bcr[4];
    #pragma unroll
    for (int g = 0; g < 4; ++g) {
        const int cg = g*128 + colh;
        bcr[g] = bc[cg];
        #pragma unroll
        for (int f = 0; f < 5; ++f) wxr[g][f] = Wc[f*512 + cg];
    }
    const float b1r = b1v[colh];
    float cst[4] = {0.f, 0.f, 0.f, 0.f};   // c state, 4 rows per lane

    const char* wtc8 = (const char*)WTc;
    const char* wt18 = (const char*)WT1;
    const char* bp0 = wtc8 + (unsigned)((0*128 + colh)*768 + kgrp*16);
    const char* bp1 = wtc8 + (unsigned)((1*128 + colh)*768 + kgrp*16);
    const char* bp2 = wtc8 + (unsigned)((2*128 + colh)*768 + kgrp*16);
    const char* bp3 = wtc8 + (unsigned)((3*128 + colh)*768 + kgrp*16);
    const char* b1p = wt18 + (unsigned)(colh*256 + kgrp*16);

    unsigned* myf = flags + blk*16;
    unsigned* lfR = flags + (blk - 8)*16 + 1;  // left's last-row flag   (deref only if ci>0)
    unsigned* rfL = flags + (blk + 8)*16 + 0;  // right's first-row flag (deref only if ci<7)
    unsigned* lfO = flags + (blk - 8)*16 + 2;  // left's out-scalar flag (deref only if ci>0)

    __syncthreads();

    for (int j = 0; j < NSTEP; ++j) {
        // ---- (a)/(b): waits, deferred nd completion, boundary loads, x staging ----
        if (j > 0) {
            if (tid == 0 && ci > 0) {
                while (__hip_atomic_load(lfR, __ATOMIC_RELAXED, __HIP_MEMORY_SCOPE_AGENT) < (unsigned)j)
                    __builtin_amdgcn_s_sleep(1);
            }
            if (tid == 1 && ci < 7) {
                while (__hip_atomic_load(rfL, __ATOMIC_RELAXED, __HIP_MEMORY_SCOPE_AGENT) < (unsigned)j)
                    __builtin_amdgcn_s_sleep(1);
            }
            if (tid == 2 && ci > 0 && j > TPRED) {
                // complete nd of step j-1 for first row (needs left's out[s0-1][0] of step j-1)
                while (__hip_atomic_load(lfO, __ATOMIC_RELAXED, __HIP_MEMORY_SCOPE_AGENT) < (unsigned)j)
                    __builtin_amdgcn_s_sleep(1);
                const float In  = __hip_atomic_load(&osc[(blk - 8)*2 + ((j - 1) & 1)],
                                                    __ATOMIC_RELAXED, __HIP_MEMORY_SCOPE_AGENT);
                const float no  = outl[0];   // own out[s0][0] of step j-1 (still valid, overwritten later)
                const float xt2 = input[(((b*NT) + (j - 1))*NS + s0)*5 + 2];
                const long base = ((long)(b*TOUT + (j - 1 - TPRED))*NS + s0)*5;
                outp[base + 1] = In;
                outp[base + 2] = xt2 + In - no;
            }
            if (tid < 32 && ci > 0) {   // left neighbor's last row -> h_loc row 0
                const unsigned long long* src =
                    (const unsigned long long*)(hbuf + (((blk - 8)*2 + 1)*2 + (j & 1))*128);
                unsigned long long v = __hip_atomic_load(src + tid, __ATOMIC_RELAXED, __HIP_MEMORY_SCOPE_AGENT);
                *(unsigned long long*)((char*)h_loc + swz((unsigned)(tid*8))) = v;
            }
            if (tid >= 32 && tid < 64 && ci < 7) {  // right neighbor's first row -> h_loc row 17
                const int t = tid - 32;
                const unsigned long long* src =
                    (const unsigned long long*)(hbuf + (((blk + 8)*2 + 0)*2 + (j & 1))*128);
                unsigned long long v = __hip_atomic_load(src + t, __ATOMIC_RELAXED, __HIP_MEMORY_SCOPE_AGENT);
                *(unsigned long long*)((char*)h_loc + swz((unsigned)(17*256 + t*8))) = v;
            }
        }
        if (tid >= 64 && tid < 64 + RROWS*5) {
            const int idx = tid - 64;
            xl[idx] = input[(((b*NT) + j)*NS + (s0 + idx/5))*5 + (idx % 5)];
        }
        if (ci == 0 && tid >= 144 && tid < 147) {
            const int q = tid - 144;
            xnl[q] = input[((b*NT) + (j + 1))*NS*5 + ((q == 0) ? 1 : (q + 2))];
        }
        __syncthreads();  // B1

        // ---- (d): z GEMM, M=16 N=4x16(gates) K=384, A contiguous in LDS, B streamed from L2 ----
        f32x4 a0 = {0.f,0.f,0.f,0.f}, a1 = {0.f,0.f,0.f,0.f}, a2 = {0.f,0.f,0.f,0.f}, a3 = {0.f,0.f,0.f,0.f};
        const unsigned aoff = (unsigned)(arow*256 + kgrp*16);
        #pragma unroll
        for (int kt = 0; kt < 12; ++kt) {
            const s16x8 av = *(const s16x8*)((const char*)h_loc + swz(aoff + kt*64));
            a0 = __builtin_amdgcn_mfma_f32_16x16x32_bf16(av, *(const s16x8*)(bp0 + kt*64), a0, 0, 0, 0);
            a1 = __builtin_amdgcn_mfma_f32_16x16x32_bf16(av, *(const s16x8*)(bp1 + kt*64), a1, 0, 0, 0);
            a2 = __builtin_amdgcn_mfma_f32_16x16x32_bf16(av, *(const s16x8*)(bp2 + kt*64), a2, 0, 0, 0);
            a3 = __builtin_amdgcn_mfma_f32_16x16x32_bf16(av, *(const s16x8*)(bp3 + kt*64), a3, 0, 0, 0);
        }
        __syncthreads();  // B2: all A-reads of h[j] done before anyone writes h[j+1]

        // ---- (e): gates fully in-register (lane owns i,f,g,o for its hid col) ----
        #pragma unroll
        for (int r = 0; r < 4; ++r) {
            const int row = kgrp*4 + r;   // C/D frag: row=(lane>>4)*4+reg
            const float xv0 = xl[row*5+0], xv1 = xl[row*5+1], xv2 = xl[row*5+2],
                        xv3 = xl[row*5+3], xv4 = xl[row*5+4];
            const float iv = a0[r] + bcr[0] + xv0*wxr[0][0] + xv1*wxr[0][1] + xv2*wxr[0][2] + xv3*wxr[0][3] + xv4*wxr[0][4];
            const float fv = a1[r] + bcr[1] + xv0*wxr[1][0] + xv1*wxr[1][1] + xv2*wxr[1][2] + xv3*wxr[1][3] + xv4*wxr[1][4];
            const float gv = a2[r] + bcr[2] + xv0*wxr[2][0] + xv1*wxr[2][1] + xv2*wxr[2][2] + xv3*wxr[2][3] + xv4*wxr[2][4];
            const float ov = a3[r] + bcr[3] + xv0*wxr[3][0] + xv1*wxr[3][1] + xv2*wxr[3][2] + xv3*wxr[3][3] + xv4*wxr[3][4];
            const float si = __builtin_amdgcn_rcpf(1.f + __expf(-iv));
            const float sf = __builtin_amdgcn_rcpf(1.f + __expf(-fv));
            const float so = __builtin_amdgcn_rcpf(1.f + __expf(-ov));
            const float tg = 1.f - 2.f*__builtin_amdgcn_rcpf(__expf(2.f*gv) + 1.f);  // tanh, inf-safe
            const float cn = sf*cst[r] + si*tg;
            cst[r] = cn;
            const float tc = 1.f - 2.f*__builtin_amdgcn_rcpf(__expf(2.f*cn) + 1.f);
            const float hn = so*tc;
            *(__hip_bfloat16*)((char*)h_loc + swz((unsigned)((row + 1)*256 + colh*2))) = __float2bfloat16(hn);
        }
        __syncthreads();  // B3: h[j+1] complete

        // ---- (f): publish boundary rows (wave0 side0, wave1 side1); other waves go straight to W1 ----
        if (w == 0 && ci > 0) {
            const unsigned v = *(const unsigned*)((const char*)h_loc + swz(256u + lane*4));
            __hip_atomic_store((unsigned*)(hbuf + ((blk*2 + 0)*2 + ((j + 1) & 1))*128) + lane, v,
                               __ATOMIC_RELAXED, __HIP_MEMORY_SCOPE_AGENT);
            __threadfence();
            if (lane == 0)
                __hip_atomic_store(myf + 0, (unsigned)(j + 1), __ATOMIC_RELAXED, __HIP_MEMORY_SCOPE_AGENT);
        }
        if (w == 1 && ci < 7) {
            const unsigned v = *(const unsigned*)((const char*)h_loc + swz(16u*256 + lane*4));
            __hip_atomic_store((unsigned*)(hbuf + ((blk*2 + 1)*2 + ((j + 1) & 1))*128) + lane, v,
                               __ATOMIC_RELAXED, __HIP_MEMORY_SCOPE_AGENT);
            __threadfence();
            if (lane == 0)
                __hip_atomic_store(myf + 1, (unsigned)(j + 1), __ATOMIC_RELAXED, __HIP_MEMORY_SCOPE_AGENT);
        }

        // ---- (g): W1 GEMM M=16 N=128 K=128 + bias + relu ----
        f32x4 acc1 = {0.f,0.f,0.f,0.f};
        const unsigned a1off = (unsigned)((arow + 1)*256 + kgrp*16);
        #pragma unroll
        for (int kt = 0; kt < 4; ++kt) {
            const s16x8 av = *(const s16x8*)((const char*)h_loc + swz(a1off + kt*64));
            acc1 = __builtin_amdgcn_mfma_f32_16x16x32_bf16(av, *(const s16x8*)(b1p + kt*64), acc1, 0, 0, 0);
        }
        #pragma unroll
        for (int r = 0; r < 4; ++r) {
            const int row = kgrp*4 + r;
            const float v = fmaxf(acc1[r] + b1r, 0.f);
            *(__hip_bfloat16*)((char*)relu_l + swz((unsigned)(row*256 + colh*2))) = __float2bfloat16(v);
        }
        __syncthreads();  // B4

        // ---- (h): W2 (N=3) on 48 lanes of wave 0, then nd epilogue on 16 lanes (same wave: DS in-order) ----
        if (tid < 48) {
            const int m = tid / 3, p = tid % 3;
            float s = b2l[p];
            #pragma unroll
            for (int kc = 0; kc < 16; ++kc) {
                union { s16x8 v; unsigned short u[8]; } uu;
                uu.v = *(const s16x8*)((const char*)relu_l + swz((unsigned)(m*256 + kc*16)));
                #pragma unroll
                for (int e = 0; e < 8; ++e)
                    s += __uint_as_float((unsigned)uu.u[e] << 16) * w2l[p*128 + kc*8 + e];
            }
            outl[m*3 + p] = s;
            if (tid == 45 && ci < 7) {   // m=15,p=0: out[last][0] for right neighbor
                __hip_atomic_store(&osc[blk*2 + (j & 1)], s, __ATOMIC_RELAXED, __HIP_MEMORY_SCOPE_AGENT);
                __threadfence();
                __hip_atomic_store(myf + 2, (unsigned)(j + 1), __ATOMIC_RELAXED, __HIP_MEMORY_SCOPE_AGENT);
            }
        }
        if (tid < 16 && j >= TPRED) {
            const int m = tid;
            const float no  = outl[m*3 + 0];
            const float sp0 = (m == 0 && ci == 0) ? xnl[1] : outl[m*3 + 1];
            const float sp1 = (m == 0 && ci == 0) ? xnl[2] : outl[m*3 + 2];
            const long base = ((long)(b*TOUT + (j - TPRED))*NS + (s0 + m))*5;
            outp[base + 0] = no;
            outp[base + 3] = sp0;
            outp[base + 4] = sp1;
            if (m > 0 || ci == 0) {      // first row of non-edge chunks deferred to next step
                const float In = (m > 0) ? outl[(m - 1)*3 + 0] : xnl[0];
                outp[base + 1] = In;
                outp[base + 2] = xl[m*5 + 2] + In - no;
            }
        }
        __syncthreads();  // B5
    }

    // drain: deferred nd for the last step (j-1 = 126)
    if (tid == 2 && ci > 0) {
        while (__hip_atomic_load(lfO, __ATOMIC_RELAXED, __HIP_MEMORY_SCOPE_AGENT) < (unsigned)NSTEP)
            __builtin_amdgcn_s_sleep(1);
        const float In  = __hip_atomic_load(&osc[(blk - 8)*2 + ((NSTEP - 1) & 1)],
                                            __ATOMIC_RELAXED, __HIP_MEMORY_SCOPE_AGENT);
        const float no  = outl[0];
        const float xt2 = input[(((b*NT) + (NSTEP - 1))*NS + s0)*5 + 2];
        const long base = ((long)(b*TOUT + (NSTEP - 1 - TPRED))*NS + s0)*5;
        outp[base + 1] = In;
        outp[base + 2] = xt2 + In - no;
    }
}

extern "C" void kernel_launch(void* const* d_in, const int* in_sizes, int n_in,
                              void* d_out, int out_size, void* d_ws, size_t ws_size,
                              hipStream_t stream) {
    const float* input = (const float*)d_in[0];
    const float* Wc    = (const float*)d_in[1];
    const float* bc    = (const float*)d_in[2];
    const float* W1    = (const float*)d_in[3];
    const float* b1    = (const float*)d_in[4];
    const float* W2    = (const float*)d_in[5];
    const float* b2    = (const float*)d_in[6];
    float* outp = (float*)d_out;
    char* ws = (char*)d_ws;

    __hip_bfloat16* WTc = (__hip_bfloat16*)(ws + WS_WTC);
    __hip_bfloat16* WT1 = (__hip_bfloat16*)(ws + WS_WT1);
    __hip_bfloat16* hb  = (__hip_bfloat16*)(ws + WS_HB);
    float*          osc = (float*)(ws + WS_OSC);
    unsigned*       flg = (unsigned*)(ws + WS_FLG);

    hipMemsetAsync(ws + WS_FLG, 0, 64*16*4, stream);
    init_weights<<<832, 256, 0, stream>>>(Wc, W1, WTc, WT1);
    lstm_persist<<<NBLK, NTHR, 0, stream>>>(input, Wc, bc, b1, W2, b2, outp,
                                            WTc, WT1, hb, osc, flg);
}